// Round 7
// baseline (328.838 us; speedup 1.0000x reference)
//
#include <hip/hip_runtime.h>
#include <hip/hip_bf16.h>
#include <stdint.h>

#define Bsz   16384
#define Tt    79
#define Dd    256
#define KP    272    // padded K: 256 h + 3 x + 1 bias + 12 zero (granularity 16)
#define LROW  280    // LDS row stride in bf16 elems (560 B)
#define NTILE 32     // batch rows per block; 512 blocks = 2 blocks/CU
#define THR   256    // 4 waves; wave wm owns m in [64*wm, 64*wm+64) as 2 32-wide tiles

typedef __attribute__((ext_vector_type(8)))  short short8;
typedef __attribute__((ext_vector_type(4)))  float float4_;
typedef __attribute__((ext_vector_type(16))) float float16_;

__device__ __forceinline__ unsigned pk2(float a, float b){
  __hip_bfloat162 h = __float22bfloat162_rn(make_float2(a, b));  // v_cvt_pk_bf16_f32
  return *(unsigned*)&h;
}
__device__ __forceinline__ unsigned short f2bf(float f){
  unsigned u = __float_as_uint(f);
  u += 0x7fffu + ((u >> 16) & 1u);
  return (unsigned short)(u >> 16);
}

// Fused single kernel: 512 blocks x 256 threads (2 blocks/CU, 2 waves/SIMD).
// Each block owns 32 batch rows; h^T (32 x 272 bf16, double-buffered) in LDS.
// Wave wm (0..3) owns m-cols [64wm, 64wm+64) as 2 32x32 tiles.
// A-frags (U^T + folded W_in/b_rnn) gathered from global at startup: 34 short8.
// K-loop uses sched_group_barrier to interleave 1 ds_read : 2 MFMA so the
// LDS pipe and matrix pipe overlap instead of serializing.
__global__ __launch_bounds__(THR, 2) void rnn_all(
    const float* __restrict__ x0,
    const float* __restrict__ x1,
    const float* __restrict__ x2,
    const float* __restrict__ W_in,
    const float* __restrict__ U,
    const float* __restrict__ b_rnn,
    const float* __restrict__ W_d,
    const float* __restrict__ b_d,
    float* __restrict__ out){
  __shared__ __align__(16) short hbuf[2][NTILE * LROW];

  const int tid  = threadIdx.x;
  const int lane = tid & 63;
  const int wm   = tid >> 6;     // 0..3: which 64-col m-chunk
  const int nl   = lane & 31;    // n (batch row) for B/C; m-within-tile for A
  const int hi   = lane >> 5;    // k half within a 16-wide k-tile
  const int hi8  = hi * 8;
  const int bbase = blockIdx.x * NTILE;

  // ---- zero both LDS buffers (h0 = 0, pads = 0) ----
  {
    int4* p = (int4*)&hbuf[0][0];
    const int tot = 2 * NTILE * LROW * 2 / 16;
    int4 z = make_int4(0, 0, 0, 0);
    for (int i = tid; i < tot; i += THR) p[i] = z;
  }
  __syncthreads();

  // bias row k=259 = 1.0 bf16 in both buffers (never overwritten)
  if (tid < NTILE){
    hbuf[0][tid * LROW + 259] = (short)0x3F80;
    hbuf[1][tid * LROW + 259] = (short)0x3F80;
  }

  // stager: 8 lanes per wave, each owns one of the block's 32 batch rows
  const bool stager = (lane < 8);
  const int  sn  = wm * 8 + (lane & 7);
  const int  sgb = bbase + sn;
  if (stager){
    int tr = Tt - 1;
    float a = x0[sgb * Tt + tr];
    float b = x1[sgb * Tt + tr];
    float c = x2[sgb * Tt + tr];
    *(unsigned*)&hbuf[0][sn * LROW + 256] = pk2(a, b);
    hbuf[0][sn * LROW + 258] = (short)f2bf(c);
  }

  // ---- A fragments gathered straight from global U (+ W_in, b_rnn) ----
  // A[m][k]: lane(nl,hi) element j -> k = kt*16 + hi8 + j, m = wm*64+mt*32+nl.
  short8 afr[2][17];
  #pragma unroll
  for (int mt = 0; mt < 2; ++mt){
    const int mcol = wm * 64 + mt * 32 + nl;
    #pragma unroll
    for (int kt = 0; kt < 16; ++kt){
      float f[8];
      #pragma unroll
      for (int j = 0; j < 8; ++j)
        f[j] = U[(kt * 16 + hi8 + j) * 256 + mcol];
      union { unsigned u[4]; short8 s; } r;
      r.u[0] = pk2(f[0], f[1]); r.u[1] = pk2(f[2], f[3]);
      r.u[2] = pk2(f[4], f[5]); r.u[3] = pk2(f[6], f[7]);
      afr[mt][kt] = r.s;
    }
    union { unsigned u[4]; short8 s; } r;
    if (hi == 0){
      r.u[0] = pk2(W_in[0 * 256 + mcol], W_in[1 * 256 + mcol]);
      r.u[1] = pk2(W_in[2 * 256 + mcol], b_rnn[mcol]);
      r.u[2] = 0; r.u[3] = 0;
    } else {
      r.u[0] = 0; r.u[1] = 0; r.u[2] = 0; r.u[3] = 0;
    }
    afr[mt][16] = r.s;
  }

  __syncthreads();

  const float16_ zz16 = {0.f,0.f,0.f,0.f,0.f,0.f,0.f,0.f,
                         0.f,0.f,0.f,0.f,0.f,0.f,0.f,0.f};

  auto step = [&](const short* __restrict__ hb, short* __restrict__ hw, int t){
    // prefetch x(t+1), hidden under the K-loop
    float xa = 0.f, xb = 0.f, xc = 0.f;
    const bool pf = stager && (t < Tt - 1);
    if (pf){
      int tr = Tt - 2 - t;
      xa = x0[sgb * Tt + tr];
      xb = x1[sgb * Tt + tr];
      xc = x2[sgb * Tt + tr];
    }

    float16_ a0, a1;
    const short* bp = &hb[nl * LROW + hi8];   // one base, imm-offset reads
    short8 bcur = *(const short8*)(bp);
    #pragma unroll
    for (int kt = 0; kt < 17; ++kt){
      short8 bnxt;
      if (kt < 16) bnxt = *(const short8*)(bp + (kt + 1) * 16);
      a0 = __builtin_amdgcn_mfma_f32_32x32x16_bf16(afr[0][kt], bcur,
                                                   kt ? a0 : zz16, 0, 0, 0);
      a1 = __builtin_amdgcn_mfma_f32_32x32x16_bf16(afr[1][kt], bcur,
                                                   kt ? a1 : zz16, 0, 0, 0);
      bcur = bnxt;
      // pin the interleave: 1 DS read then 2 MFMA per k-tile
      __builtin_amdgcn_sched_group_barrier(0x100, 1, 0);  // DS read
      __builtin_amdgcn_sched_group_barrier(0x008, 2, 0);  // MFMA x2
    }

    // relu + pack + write h(t+1); reg group g holds rows m = 8g + 4hi + 0..3
    short* wr0 = &hw[nl * LROW + wm * 64 + 4 * hi];
    #pragma unroll
    for (int g = 0; g < 4; ++g){
      uint2 w;
      w.x = pk2(fmaxf(a0[4*g+0], 0.f), fmaxf(a0[4*g+1], 0.f));
      w.y = pk2(fmaxf(a0[4*g+2], 0.f), fmaxf(a0[4*g+3], 0.f));
      *(uint2*)(wr0 + 8 * g) = w;
      w.x = pk2(fmaxf(a1[4*g+0], 0.f), fmaxf(a1[4*g+1], 0.f));
      w.y = pk2(fmaxf(a1[4*g+2], 0.f), fmaxf(a1[4*g+3], 0.f));
      *(uint2*)(wr0 + 32 + 8 * g) = w;
    }
    if (pf){
      *(unsigned*)&hw[sn * LROW + 256] = pk2(xa, xb);
      hw[sn * LROW + 258] = (short)f2bf(xc);
    }
    __syncthreads();
  };

  // ---- 79 steps: explicit ping-pong (loop-invariant LDS bases) ----
  #pragma unroll 1
  for (int t = 0; t < Tt - 1; t += 2){
    step(&hbuf[0][0], &hbuf[1][0], t);
    step(&hbuf[1][0], &hbuf[0][0], t + 1);
  }
  step(&hbuf[0][0], &hbuf[1][0], Tt - 1);   // t = 78 (even), final h -> buf 1

  // ---- epilogue: out^T = W_d^T h^T + b_d; W_d gathered just-in-time ----
  const short* hb = &hbuf[1][0];
  float16_ o0, o1;
  #pragma unroll
  for (int kt = 0; kt < 17; ++kt){
    short8 wf[2];
    #pragma unroll
    for (int mt = 0; mt < 2; ++mt){
      const int mcol = wm * 64 + mt * 32 + nl;
      union { unsigned u[4]; short8 s; } r;
      if (kt < 16){
        float f[8];
        #pragma unroll
        for (int j = 0; j < 8; ++j)
          f[j] = W_d[(kt * 16 + hi8 + j) * 256 + mcol];
        r.u[0] = pk2(f[0], f[1]); r.u[1] = pk2(f[2], f[3]);
        r.u[2] = pk2(f[4], f[5]); r.u[3] = pk2(f[6], f[7]);
      } else {
        if (hi == 0){ r.u[0] = 0; r.u[1] = pk2(0.f, b_d[mcol]); r.u[2] = 0; r.u[3] = 0; }
        else        { r.u[0] = 0; r.u[1] = 0;                   r.u[2] = 0; r.u[3] = 0; }
      }
      wf[mt] = r.s;
    }
    short8 b = *(const short8*)&hb[nl * LROW + kt * 16 + hi8];
    o0 = __builtin_amdgcn_mfma_f32_32x32x16_bf16(wf[0], b, kt ? o0 : zz16, 0, 0, 0);
    o1 = __builtin_amdgcn_mfma_f32_32x32x16_bf16(wf[1], b, kt ? o1 : zz16, 0, 0, 0);
  }
  #pragma unroll
  for (int g = 0; g < 4; ++g){
    int m0 = wm * 64 + 8 * g + 4 * hi;
    float4_ v0 = {o0[4*g+0], o0[4*g+1], o0[4*g+2], o0[4*g+3]};
    float4_ v1 = {o1[4*g+0], o1[4*g+1], o1[4*g+2], o1[4*g+3]};
    *(float4_*)&out[(bbase + nl) * Dd + m0]      = v0;
    *(float4_*)&out[(bbase + nl) * Dd + m0 + 32] = v1;
  }
}

extern "C" void kernel_launch(void* const* d_in, const int* in_sizes, int n_in,
                              void* d_out, int out_size, void* d_ws, size_t ws_size,
                              hipStream_t stream){
  const float* x0    = (const float*)d_in[0];
  const float* x1    = (const float*)d_in[1];
  const float* x2    = (const float*)d_in[2];
  const float* W_in  = (const float*)d_in[3];
  const float* U     = (const float*)d_in[4];
  const float* b_rnn = (const float*)d_in[5];
  const float* W_d   = (const float*)d_in[6];
  const float* b_d   = (const float*)d_in[7];
  float* out = (float*)d_out;

  rnn_all<<<Bsz / NTILE, THR, 0, stream>>>(x0, x1, x2, W_in, U, b_rnn, W_d, b_d, out);
}

// Round 8
// 215.950 us; speedup vs baseline: 1.5228x; 1.5228x over previous
//
#include <hip/hip_runtime.h>
#include <hip/hip_bf16.h>
#include <stdint.h>

#define Bsz   16384
#define Tt    79
#define Dd    256
#define KP    272    // padded K: 256 h + 3 x + 1 bias + 12 zero (granularity 16)
#define LROW  280    // LDS row stride in bf16 elems (560 B)
#define NTILE 32     // batch rows per block; 512 blocks = 2 blocks/CU
#define THR   256    // 4 waves; wave wm owns m in [64*wm, 64*wm+64) as 2 32-wide tiles

typedef __attribute__((ext_vector_type(8)))  short short8;
typedef __attribute__((ext_vector_type(4)))  float float4_;
typedef __attribute__((ext_vector_type(16))) float float16_;

__device__ __forceinline__ unsigned pk2(float a, float b){
  __hip_bfloat162 h = __float22bfloat162_rn(make_float2(a, b));  // v_cvt_pk_bf16_f32
  return *(unsigned*)&h;
}
__device__ __forceinline__ unsigned short f2bf(float f){
  unsigned u = __float_as_uint(f);
  u += 0x7fffu + ((u >> 16) & 1u);
  return (unsigned short)(u >> 16);
}

// Ut (256 x 272): Ut[m][k] = U[k][m] (k<256), W_in[k-256][m] (256..258),
//                 b_rnn[m] (k=259), 0 pad. Wdt same with W_d / b_d.
__global__ void build_tables(const float* __restrict__ W_in,
                             const float* __restrict__ U,
                             const float* __restrict__ b_rnn,
                             const float* __restrict__ W_d,
                             const float* __restrict__ b_d,
                             unsigned short* __restrict__ Ut,
                             unsigned short* __restrict__ Wdt){
  const int TBL = 256 * KP;
  int idx = blockIdx.x * 256 + threadIdx.x;
  if (idx >= 2 * TBL) return;
  int tb  = idx / TBL;
  int rem = idx - tb * TBL;
  int m = rem / KP;
  int k = rem - m * KP;
  float v = 0.f;
  if (tb == 0){
    if      (k < 256) v = U[k * 256 + m];
    else if (k < 259) v = W_in[(k - 256) * 256 + m];
    else if (k == 259) v = b_rnn[m];
  } else {
    if      (k < 256) v = W_d[k * 256 + m];
    else if (k == 259) v = b_d[m];
  }
  unsigned short o = f2bf(v);
  if (tb == 0) Ut[rem] = o; else Wdt[rem] = o;
}

// 512 blocks x 256 threads (2 blocks/CU, 2 waves/SIMD). h^T (32 x 272 bf16,
// double-buffered) in LDS. NO global traffic inside the t-loop: all x values
// pre-staged (time-reversed, bf16, bias=1.0 in slot 3) into LDS at startup.
// Wave wm (0..3) owns m-cols [64wm, 64wm+64) as 2 32x32 tiles; 32x32x16 MFMA.
__global__ __launch_bounds__(THR, 2) void rnn_main(
    const float* __restrict__ x0,
    const float* __restrict__ x1,
    const float* __restrict__ x2,
    const unsigned short* __restrict__ Ut,
    const unsigned short* __restrict__ Wdt,
    float* __restrict__ out){
  __shared__ __align__(16) short hbuf[2][NTILE * LROW];
  __shared__ __align__(8)  short xs[Tt * NTILE * 4];  // [t][n][{x0,x1,x2,bias}]

  const int tid  = threadIdx.x;
  const int lane = tid & 63;
  const int wm   = tid >> 6;     // 0..3: which 64-col m-chunk
  const int nl   = lane & 31;    // n (batch row) for B/C; m-within-tile for A
  const int hi   = lane >> 5;    // k half within a 16-wide k-tile
  const int hi8  = hi * 8;
  const int bbase = blockIdx.x * NTILE;

  // ---- zero both h buffers (h0 = 0, pad rows = 0) ----
  {
    int4* p = (int4*)&hbuf[0][0];
    const int tot = 2 * NTILE * LROW * 2 / 16;
    int4 z = make_int4(0, 0, 0, 0);
    for (int i = tid; i < tot; i += THR) p[i] = z;
  }

  // ---- stage all x into LDS (time-reversed), bias=1.0 in slot 3 ----
  {
    const int n  = tid >> 3;        // 0..31 batch row within block
    const int tc = tid & 7;         // 0..7 t-phase
    const float* s0 = x0 + (bbase + n) * Tt;
    const float* s1 = x1 + (bbase + n) * Tt;
    const float* s2 = x2 + (bbase + n) * Tt;
    for (int t = tc; t < Tt; t += 8){
      int d = ((Tt - 1 - t) * NTILE + n) * 4;   // reversed time index
      xs[d + 0] = f2bf(s0[t]);
      xs[d + 1] = f2bf(s1[t]);
      xs[d + 2] = f2bf(s2[t]);
      xs[d + 3] = (short)0x3F80;                // bias row (k=259) = 1.0
    }
  }

  // ---- A fragments from prebuilt Ut: 2 mt x 17 kt = 34 short8 ----
  short8 afr[2][17];
  #pragma unroll
  for (int mt = 0; mt < 2; ++mt){
    const unsigned short* p = Ut + (wm * 64 + mt * 32 + nl) * KP + hi8;
    #pragma unroll
    for (int kt = 0; kt < 17; ++kt){
      afr[mt][kt] = *(const short8*)(p + kt * 16);
    }
  }

  __syncthreads();

  // stager lanes: 8 per wave, each owns one of the block's 32 batch rows
  const bool stager = (lane < 8);
  const int  sn = wm * 8 + (lane & 7);
  if (stager){   // x(t=0) + bias -> buf 0
    uint2 v = *(const uint2*)&xs[(0 * NTILE + sn) * 4];
    *(uint2*)&hbuf[0][sn * LROW + 256] = v;
  }
  __syncthreads();

  const float16_ zz16 = {0.f,0.f,0.f,0.f,0.f,0.f,0.f,0.f,
                         0.f,0.f,0.f,0.f,0.f,0.f,0.f,0.f};

  auto step = [&](const short* __restrict__ hb, short* __restrict__ hw, int t){
    // x(t+1) from LDS staging (no global traffic in the loop)
    uint2 xv;
    const bool pf = stager && (t < Tt - 1);
    if (pf) xv = *(const uint2*)&xs[((t + 1) * NTILE + sn) * 4];

    float16_ a0, a1;
    const short* bp = &hb[nl * LROW + hi8];   // one base, imm-offset reads
    #pragma unroll
    for (int kt = 0; kt < 17; ++kt){
      short8 b = *(const short8*)(bp + kt * 16);
      a0 = __builtin_amdgcn_mfma_f32_32x32x16_bf16(afr[0][kt], b,
                                                   kt ? a0 : zz16, 0, 0, 0);
      a1 = __builtin_amdgcn_mfma_f32_32x32x16_bf16(afr[1][kt], b,
                                                   kt ? a1 : zz16, 0, 0, 0);
    }

    // relu + pack + write h(t+1); reg group g holds rows m = 8g + 4hi + 0..3
    short* wr0 = &hw[nl * LROW + wm * 64 + 4 * hi];
    #pragma unroll
    for (int g = 0; g < 4; ++g){
      uint2 w;
      w.x = pk2(fmaxf(a0[4*g+0], 0.f), fmaxf(a0[4*g+1], 0.f));
      w.y = pk2(fmaxf(a0[4*g+2], 0.f), fmaxf(a0[4*g+3], 0.f));
      *(uint2*)(wr0 + 8 * g) = w;
      w.x = pk2(fmaxf(a1[4*g+0], 0.f), fmaxf(a1[4*g+1], 0.f));
      w.y = pk2(fmaxf(a1[4*g+2], 0.f), fmaxf(a1[4*g+3], 0.f));
      *(uint2*)(wr0 + 32 + 8 * g) = w;
    }
    if (pf) *(uint2*)&hw[sn * LROW + 256] = xv;   // x(t+1) + bias
    __syncthreads();
  };

  // ---- 79 steps: explicit ping-pong (loop-invariant LDS bases) ----
  #pragma unroll 1
  for (int t = 0; t < Tt - 1; t += 2){
    step(&hbuf[0][0], &hbuf[1][0], t);
    step(&hbuf[1][0], &hbuf[0][0], t + 1);
  }
  step(&hbuf[0][0], &hbuf[1][0], Tt - 1);   // t = 78 (even), final h -> buf 1

  // ---- epilogue: out^T = W_d^T h^T + b_d (Wdt zero at k=256..258 kills
  //      the stale x rows in buf1; k=259 bias=1.0 was written by step 77) ----
  const short* hb = &hbuf[1][0];
  float16_ o0, o1;
  #pragma unroll
  for (int kt = 0; kt < 17; ++kt){
    short8 w0 = *(const short8*)(Wdt + (wm * 64 +      nl) * KP + kt * 16 + hi8);
    short8 w1 = *(const short8*)(Wdt + (wm * 64 + 32 + nl) * KP + kt * 16 + hi8);
    short8 b  = *(const short8*)&hb[nl * LROW + kt * 16 + hi8];
    o0 = __builtin_amdgcn_mfma_f32_32x32x16_bf16(w0, b, kt ? o0 : zz16, 0, 0, 0);
    o1 = __builtin_amdgcn_mfma_f32_32x32x16_bf16(w1, b, kt ? o1 : zz16, 0, 0, 0);
  }
  #pragma unroll
  for (int g = 0; g < 4; ++g){
    int m0 = wm * 64 + 8 * g + 4 * hi;
    float4_ v0 = {o0[4*g+0], o0[4*g+1], o0[4*g+2], o0[4*g+3]};
    float4_ v1 = {o1[4*g+0], o1[4*g+1], o1[4*g+2], o1[4*g+3]};
    *(float4_*)&out[(bbase + nl) * Dd + m0]      = v0;
    *(float4_*)&out[(bbase + nl) * Dd + m0 + 32] = v1;
  }
}

extern "C" void kernel_launch(void* const* d_in, const int* in_sizes, int n_in,
                              void* d_out, int out_size, void* d_ws, size_t ws_size,
                              hipStream_t stream){
  const float* x0    = (const float*)d_in[0];
  const float* x1    = (const float*)d_in[1];
  const float* x2    = (const float*)d_in[2];
  const float* W_in  = (const float*)d_in[3];
  const float* U     = (const float*)d_in[4];
  const float* b_rnn = (const float*)d_in[5];
  const float* W_d   = (const float*)d_in[6];
  const float* b_d   = (const float*)d_in[7];

  unsigned short* Ut  = (unsigned short*)d_ws;
  unsigned short* Wdt = Ut + 256 * KP;
  float* out = (float*)d_out;

  build_tables<<<(2 * 256 * KP + 255) / 256, 256, 0, stream>>>(W_in, U, b_rnn, W_d, b_d, Ut, Wdt);
  rnn_main<<<Bsz / NTILE, THR, 0, stream>>>(x0, x1, x2, Ut, Wdt, out);
}